// Round 12
// baseline (313.673 us; speedup 1.0000x reference)
//
#include <hip/hip_runtime.h>

#define N_NODES 50000
#define N_EDGES 1600000
#define DIM 64
#define NBK 196          // buckets of 256 dst-nodes
#define BIN_BLOCKS 391   // ceil(1.6M / 4096)
#define CSR_CAP 12288    // per-bucket slots
#define QCAP 3072        // per-quarter slots (mult-16-padded mean ~2530, ~9-sigma margin)
#define GEMM_BLOCKS 197  // covers 50000 rows + dummy zero row
#define NB_AGG 12500     // aggregate blocks per plane (4 nodes/block)
#define PLANE ((size_t)(N_NODES + 1) * 32)  // one feature-half plane, bf16 elems (64B rows)

// f32 -> bf16 round-to-nearest-even
__device__ __forceinline__ unsigned short f2bf(float f) {
    union { float f; unsigned u; } v; v.f = f;
    unsigned r = v.u + 0x7FFF + ((v.u >> 16) & 1);
    return (unsigned short)(r >> 16);
}
__device__ __forceinline__ float bf_lo(unsigned u) {
    union { unsigned u; float f; } v; v.u = u << 16;  return v.f;
}
__device__ __forceinline__ float bf_hi(unsigned u) {
    union { unsigned u; float f; } v; v.u = u & 0xFFFF0000u;  return v.f;
}

// Fused: blocks [0, BIN_BLOCKS) bin edges (R6-proven; bcur zero-based, memset
// first); blocks [BIN_BLOCKS, ..) compute plane-split T = feat @ W1^T (bf16).
__global__ __launch_bounds__(256) void bin_and_gemm1(const int* __restrict__ src,
                                                     const int* __restrict__ dst,
                                                     int* __restrict__ bcur,
                                                     int* __restrict__ binned,
                                                     const float* __restrict__ X,
                                                     const float* __restrict__ W,
                                                     unsigned short* __restrict__ T0,
                                                     unsigned short* __restrict__ T1) {
    __shared__ int cnt[NBK];
    __shared__ int lofs[NBK];
    __shared__ int shiftv[NBK];
    __shared__ int sb[256];
    __shared__ int stag[4096];
    __shared__ unsigned char stb[4096];
    __shared__ float Ws[64 * 64];
    int tid = threadIdx.x;

    if (blockIdx.x >= BIN_BLOCKS) {
        // ---------------- GEMM path (feat f32 -> T planes bf16) ----------------
#pragma unroll
        for (int j = 0; j < 16; ++j) Ws[j * 256 + tid] = W[j * 256 + tid];
        __syncthreads();

        int n = (blockIdx.x - BIN_BLOCKS) * 256 + tid;
        if (n > N_NODES) return;
        ushort4* t0 = (ushort4*)(T0 + (size_t)n * 32);
        ushort4* t1 = (ushort4*)(T1 + (size_t)n * 32);
        if (n == N_NODES) {  // dummy zero row (pad target)
            ushort4 z = {0, 0, 0, 0};
#pragma unroll
            for (int k = 0; k < 8; ++k) { t0[k] = z; t1[k] = z; }
            return;
        }

        float4 x[16];
        const float4* xp = (const float4*)(X + (size_t)n * 64);
#pragma unroll
        for (int k = 0; k < 16; ++k) x[k] = xp[k];

        for (int fg = 0; fg < 16; ++fg) {
            float r[4];
#pragma unroll
            for (int fi = 0; fi < 4; ++fi) {
                int f = fg * 4 + fi;
                float acc = 0.f;
#pragma unroll
                for (int k4 = 0; k4 < 16; ++k4) {
                    float4 w = *(const float4*)&Ws[f * 64 + k4 * 4];
                    float4 xv = x[k4];
                    acc += xv.x * w.x + xv.y * w.y + xv.z * w.z + xv.w * w.w;
                }
                r[fi] = acc;
            }
            ushort4 o;
            o.x = f2bf(r[0]); o.y = f2bf(r[1]); o.z = f2bf(r[2]); o.w = f2bf(r[3]);
            if (fg < 8) t0[fg] = o; else t1[fg - 8] = o;
        }
        return;
    }

    // ---------------- Binning path (R6-proven) ----------------
    if (tid < NBK) cnt[tid] = 0;
    __syncthreads();

    int base = blockIdx.x * 4096;
    int nedge = N_EDGES - base;
    if (nedge > 4096) nedge = 4096;

    int myb[16], myr[16], myp[16];
#pragma unroll
    for (int i = 0; i < 16; ++i) {
        int e = base + i * 256 + tid;
        myb[i] = -1;
        if (e < N_EDGES) {
            int s = src[e], d = dst[e];
            int b = d >> 8;
            myb[i] = b;
            myp[i] = ((d & 255) << 16) | s;
            myr[i] = atomicAdd(&cnt[b], 1);
        }
    }
    __syncthreads();

    int c = (tid < NBK) ? cnt[tid] : 0;
    sb[tid] = c;
    __syncthreads();
    for (int off = 1; off < 256; off <<= 1) {
        int u = (tid >= off) ? sb[tid - off] : 0;
        __syncthreads();
        sb[tid] += u;
        __syncthreads();
    }
    if (tid < NBK) {
        lofs[tid] = sb[tid] - c;
        if (c) shiftv[tid] = tid * CSR_CAP + atomicAdd(&bcur[tid * 16], c) - lofs[tid];
    }
    __syncthreads();

#pragma unroll
    for (int i = 0; i < 16; ++i) {
        if (myb[i] >= 0) {
            int idx = lofs[myb[i]] + myr[i];
            stag[idx] = myp[i];
            stb[idx] = (unsigned char)myb[i];
        }
    }
    __syncthreads();

    for (int i = tid; i < nedge; i += 256)
        binned[i + shiftv[stb[i]]] = stag[i];
}

// One workgroup per (bucket, dst-quarter). Counts padded to MULT-16 with dummy
// src = N_NODES (zero row). nodeinfo = (padded_cnt << 23) | pos, pos%16==0.
__global__ __launch_bounds__(256) void build_csr(const int* __restrict__ binned,
                                                 const int* __restrict__ bcur,
                                                 unsigned* __restrict__ nodeinfo,
                                                 unsigned short* __restrict__ csr16) {
    __shared__ int cnt[64], cnt2[64], ofs[64], sb[64];
    __shared__ int qtot;
    int tid = threadIdx.x;
    int b = blockIdx.x >> 2;
    int q = blockIdx.x & 3;
    int ibase = b * CSR_CAP;
    int qbase = (b * 4 + q) * QCAP;
    int m = bcur[b * 16];          // zero-based count
    if (m > CSR_CAP) m = CSR_CAP;
    if (tid < 64) { cnt[tid] = 0; cnt2[tid] = 0; }
    __syncthreads();

    for (int i = tid; i < m; i += 256) {
        int dl = (binned[ibase + i] >> 16) & 255;
        if ((dl >> 6) == q) atomicAdd(&cnt[dl & 63], 1);
    }
    __syncthreads();

    int v = 0;
    if (tid < 64) { v = (cnt[tid] + 15) & ~15; sb[tid] = v; }  // mult-16 pad
    __syncthreads();
    for (int off = 1; off < 64; off <<= 1) {
        int u = (tid >= off && tid < 64) ? sb[tid - off] : 0;
        __syncthreads();
        if (tid < 64) sb[tid] += u;
        __syncthreads();
    }
    if (tid < 64) {
        ofs[tid] = sb[tid] - v;
        int node = (b << 8) + (q << 6) + tid;
        if (node < N_NODES)
            nodeinfo[node] = ((unsigned)v << 23) | (unsigned)(qbase + ofs[tid]);
    }
    if (tid == 63) qtot = sb[63];
    __syncthreads();

    int qt = qtot;
    for (int i = tid; i < qt; i += 256) csr16[qbase + i] = (unsigned short)N_NODES;
    __syncthreads();

    for (int i = tid; i < m; i += 256) {
        int p = binned[ibase + i];
        int dl = (p >> 16) & 255;
        if ((dl >> 6) == q) {
            int r = atomicAdd(&cnt2[dl & 63], 1);
            csr16[qbase + ofs[dl & 63] + r] = (unsigned short)(p & 0xFFFF);
        }
    }
}

// Plane-split T = X(bf16 [node][64]) @ W^T; dummy row zeroed. (layer 2)
__global__ __launch_bounds__(256) void gemm64_bf16(const unsigned short* __restrict__ X,
                                                   const float* __restrict__ W,
                                                   unsigned short* __restrict__ T0,
                                                   unsigned short* __restrict__ T1,
                                                   int n_rows) {
    __shared__ float Ws[64 * 64];
    int tid = threadIdx.x;
#pragma unroll
    for (int j = 0; j < 16; ++j) Ws[j * 256 + tid] = W[j * 256 + tid];
    __syncthreads();

    int n = blockIdx.x * 256 + tid;
    if (n > n_rows) return;
    ushort4* t0 = (ushort4*)(T0 + (size_t)n * 32);
    ushort4* t1 = (ushort4*)(T1 + (size_t)n * 32);
    if (n == n_rows) {
        ushort4 z = {0, 0, 0, 0};
#pragma unroll
        for (int k = 0; k < 8; ++k) { t0[k] = z; t1[k] = z; }
        return;
    }

    uint4 xr[8];  // 64 bf16 = 128 B = 8 uint4
    const uint4* xp = (const uint4*)(X + (size_t)n * 64);
#pragma unroll
    for (int k = 0; k < 8; ++k) xr[k] = xp[k];
    float x[64];
    const unsigned* xu = (const unsigned*)xr;
#pragma unroll
    for (int p = 0; p < 32; ++p) {
        unsigned u = xu[p];
        x[2 * p] = bf_lo(u);
        x[2 * p + 1] = bf_hi(u);
    }

    const float4* xv4 = (const float4*)x;
    for (int fg = 0; fg < 16; ++fg) {
        float r[4];
#pragma unroll
        for (int fi = 0; fi < 4; ++fi) {
            int f = fg * 4 + fi;
            float acc = 0.f;
#pragma unroll
            for (int k4 = 0; k4 < 16; ++k4) {
                float4 w = *(const float4*)&Ws[f * 64 + k4 * 4];
                float4 xv = xv4[k4];
                acc += xv.x * w.x + xv.y * w.y + xv.z * w.z + xv.w * w.w;
            }
            r[fi] = acc;
        }
        ushort4 o;
        o.x = f2bf(r[0]); o.y = f2bf(r[1]); o.z = f2bf(r[2]); o.w = f2bf(r[3]);
        if (fg < 8) t0[fg] = o; else t1[fg - 8] = o;
    }
}

// One wave per (node, plane). Plane rows are 64 B (L2-resident 3.2 MB).
// Lane: j = lane>>2 (row slot 0..15), s4 = lane&3 (16B feature slice).
// One gather instr = 64 lanes x uint4 = 16 rows = 1 KB. Counts mult-16.
// Grid = 2*NB_AGG; plane-0 blocks dispatch first -> L2 holds active plane.
// mode 0: f32 out. mode 1: tanh + bf16 out.
__global__ __launch_bounds__(256) void aggregate(const unsigned short* __restrict__ T0,
                                                 const unsigned short* __restrict__ T1,
                                                 const unsigned short* __restrict__ csr,
                                                 const unsigned* __restrict__ nodeinfo,
                                                 const float* __restrict__ bias,
                                                 void* __restrict__ outp,
                                                 int mode) {
    int bidx = blockIdx.x;
    int half = 0;
    if (bidx >= NB_AGG) { half = 1; bidx -= NB_AGG; }
    int node = bidx * 4 + (threadIdx.x >> 6);
    int lane = threadIdx.x & 63;
    unsigned info = nodeinfo[node];
    int pos = (int)(info & 0x7FFFFFu);
    int iters = (int)(info >> 23) >> 4;   // groups of 16 rows
    int j = lane >> 2;
    int s4 = lane & 3;
    int c = (j >> 1) & 3;
    const uint4* ix = (const uint4*)(csr + pos);  // 32B-aligned
    const char* Tb = (const char*)(half ? T1 : T0);
    int fb = s4 * 16;

    float a0 = 0.f, a1 = 0.f, a2 = 0.f, a3 = 0.f,
          a4 = 0.f, a5 = 0.f, a6 = 0.f, a7 = 0.f;
    for (int g = 0; g < iters; ++g) {
        uint4 ia = ix[2 * g];
        uint4 ib = ix[2 * g + 1];
        uint4 sel = (j & 8) ? ib : ia;
        unsigned w = (c == 0) ? sel.x : (c == 1) ? sel.y : (c == 2) ? sel.z : sel.w;
        unsigned s = (j & 1) ? (w >> 16) : (w & 0xFFFFu);
        uint4 r = *(const uint4*)(Tb + (size_t)s * 64 + fb);
        a0 += bf_lo(r.x); a1 += bf_hi(r.x);
        a2 += bf_lo(r.y); a3 += bf_hi(r.y);
        a4 += bf_lo(r.z); a5 += bf_hi(r.z);
        a6 += bf_lo(r.w); a7 += bf_hi(r.w);
    }
    // reduce over row slots (lane bits 2..5); s4 preserved
#pragma unroll
    for (int mask = 4; mask <= 32; mask <<= 1) {
        a0 += __shfl_xor(a0, mask, 64);
        a1 += __shfl_xor(a1, mask, 64);
        a2 += __shfl_xor(a2, mask, 64);
        a3 += __shfl_xor(a3, mask, 64);
        a4 += __shfl_xor(a4, mask, 64);
        a5 += __shfl_xor(a5, mask, 64);
        a6 += __shfl_xor(a6, mask, 64);
        a7 += __shfl_xor(a7, mask, 64);
    }
    if (lane < 4) {  // lane == s4: owns features [half*32 + lane*8, +8)
        int col0 = half * 32 + lane * 8;
        float av[8] = {a0, a1, a2, a3, a4, a5, a6, a7};
#pragma unroll
        for (int k = 0; k < 8; ++k) av[k] += bias[col0 + k];
        if (mode) {
            unsigned short hb[8];
#pragma unroll
            for (int k = 0; k < 8; ++k) {
                float e = __expf(2.f * av[k]);
                hb[k] = f2bf(1.f - 2.f / (e + 1.f));
            }
            ushort4* hp = (ushort4*)&((unsigned short*)outp)[(size_t)node * DIM + col0];
            hp[0] = make_ushort4(hb[0], hb[1], hb[2], hb[3]);
            hp[1] = make_ushort4(hb[4], hb[5], hb[6], hb[7]);
        } else {
            float4* op = (float4*)&((float*)outp)[(size_t)node * DIM + col0];
            op[0] = make_float4(av[0], av[1], av[2], av[3]);
            op[1] = make_float4(av[4], av[5], av[6], av[7]);
        }
    }
}

extern "C" void kernel_launch(void* const* d_in, const int* in_sizes, int n_in,
                              void* d_out, int out_size, void* d_ws, size_t ws_size,
                              hipStream_t stream) {
    const float* feat = (const float*)d_in[0];
    const int*   src  = (const int*)d_in[1];
    const int*   dst  = (const int*)d_in[2];
    const float* W1   = (const float*)d_in[3];
    const float* b1   = (const float*)d_in[4];
    const float* W2   = (const float*)d_in[5];
    const float* b2   = (const float*)d_in[6];

    // ws layout (~21.3 MB)
    int*            binned   = (int*)d_ws;                                // 196*12288 ints
    unsigned short* csr16    = (unsigned short*)(binned + NBK * CSR_CAP); // 784*3072 ushort
    unsigned*       nodeinfo = (unsigned*)(csr16 + NBK * 4 * QCAP);       // 50000
    int*            bcur     = (int*)(nodeinfo + N_NODES);                // 196*16
    unsigned short* T0       = (unsigned short*)(bcur + NBK * 16 + 8);    // plane 0
    unsigned short* T1       = T0 + PLANE;                                 // plane 1

    unsigned short* h = (unsigned short*)d_out;  // bf16 h staged in d_out
    float* out = (float*)d_out;

    // ---- CSR build + layer-1 transform (overlapped) ----
    hipMemsetAsync(bcur, 0, NBK * 16 * sizeof(int), stream);
    bin_and_gemm1<<<BIN_BLOCKS + GEMM_BLOCKS, 256, 0, stream>>>(
        src, dst, bcur, binned, feat, W1, T0, T1);
    build_csr<<<NBK * 4, 256, 0, stream>>>(binned, bcur, nodeinfo, csr16);

    // ---- Layer 1 aggregate: h = tanh(agg + b1), bf16 -> d_out ----
    aggregate<<<2 * NB_AGG, 256, 0, stream>>>(T0, T1, csr16, nodeinfo, b1, h, 1);

    // ---- Layer 2: out = agg(h @ W2^T) + b2, f32 ----
    gemm64_bf16<<<GEMM_BLOCKS, 256, 0, stream>>>(h, W2, T0, T1, N_NODES);
    aggregate<<<2 * NB_AGG, 256, 0, stream>>>(T0, T1, csr16, nodeinfo, b2, out, 0);
}